// Round 5
// baseline (942.643 us; speedup 1.0000x reference)
//
#include <hip/hip_runtime.h>
#include <cstdint>
#include <cstddef>

// I/O fp32; intermediates bf16; math fp32.
typedef __bf16 bf16x8 __attribute__((ext_vector_type(8)));
typedef float  f32x4  __attribute__((ext_vector_type(4)));
typedef unsigned short u16x8 __attribute__((ext_vector_type(8)));

__device__ __forceinline__ float bf2f(unsigned short u) {
  union { unsigned int u; float f; } v; v.u = ((unsigned int)u) << 16; return v.f;
}
__device__ __forceinline__ unsigned short f2bf(float f) {
  union { float f; unsigned int u; } v; v.f = f;
  return (unsigned short)((v.u + 0x7fffu + ((v.u >> 16) & 1u)) >> 16);
}
__device__ __forceinline__ bf16x8 as_bf(u16x8 u) {
  union { u16x8 a; bf16x8 b; } v; v.a = u; return v.b;
}
__device__ __forceinline__ void g2lds16(const void* g, void* l) {
  __builtin_amdgcn_global_load_lds((__attribute__((address_space(1))) void*)g,
                                   (__attribute__((address_space(3))) void*)l,
                                   16, 0, 0);
}

// ---------- persistent 256x256 deep-pipelined GEMM ----------
// grid = 256 blocks; flat cross-tile pipeline (tail stages of tile i are the
// prologue of tile i+1; NT even keeps buffer parity). 8 waves (2M x 4N), BK=64,
// 2 LDS bufs (128 KiB), 4 phases/K-step. ONE counted vmcnt(4) per K-step (at
// P3 end) — loads stay in flight across all other barriers. MFMA clusters are
// ks-outer: 8 independent accumulators between same-acc reuse (no RAW chain).
// EPI: 0=+bias, 1=+bias+gelu(exp2+rcp).
template<int EPI>
__global__ __launch_bounds__(512, 2) void gemm256(
    const unsigned short* __restrict__ A, const unsigned short* __restrict__ BT,
    const float* __restrict__ bias, unsigned short* __restrict__ C,
    int N, int K, int nbx, int T)
{
  __shared__ __align__(16) unsigned short lds[2][2][2][128 * 64];  // [buf][A/B][Shalf][128x64]
  const int tid = threadIdx.x;
  const int wave = tid >> 6, lane = tid & 63;
  const int lm = lane & 15, quad = lane >> 4;
  const int wm2 = wave >> 2, wn4 = wave & 3;
  const int ex = (lm & 7) << 3;   // read-side swizzle xor (elems)

  const int NT = K >> 6;
  const int cpx = T >> 3;
  const int nit = T >> 8;         // tiles per block (grid = 256)

  const int sl8 = lane >> 3;
  const int scol = ((lane & 7) ^ sl8) << 3;       // inverse-swizzled source col (elems)
  const int r0 = wave * 8 + sl8;                  // 0..63
  const int aro = r0;                              // A region row
  const int bro = (r0 >> 5) * 64 + (r0 & 31);      // B region row

  auto stA = [&](const unsigned short* Ab, int bf, int sh, int koff) {
    const unsigned short* s = Ab + (size_t)(sh * 64) * K + koff;
    g2lds16(s,                   &lds[bf][0][sh][wave * 512]);
    g2lds16(s + (size_t)128 * K, &lds[bf][0][sh][4096 + wave * 512]);
  };
  auto stB = [&](const unsigned short* Bb, int bf, int sh, int koff) {
    const unsigned short* s = Bb + (size_t)(sh * 32) * K + koff;
    g2lds16(s,                   &lds[bf][1][sh][wave * 512]);
    g2lds16(s + (size_t)128 * K, &lds[bf][1][sh][4096 + wave * 512]);
  };

  // tile 0
  int v = blockIdx.x;
  int wg = (v & 7) * cpx + (v >> 3);
  int bm = wg / nbx, bn = wg % nbx;
  const unsigned short* curA = A + (size_t)(bm * 256 + aro) * K + scol;
  const unsigned short* curB = BT + (size_t)(bn * 256 + bro) * K + scol;

  f32x4 acc[8][4];
  bf16x8 a[4][2], b0[2][2], b1[2][2];

  // ---- prologue: steps 0 and 1 of tile 0 (NT >= 2 always here)
  stA(curA, 0, 0, 0); stB(curB, 0, 0, 0); stB(curB, 0, 1, 0); stA(curA, 0, 1, 0);
  stA(curA, 1, 0, 64); stB(curB, 1, 0, 64);
  asm volatile("s_waitcnt vmcnt(4)" ::: "memory");
  __builtin_amdgcn_s_barrier();

  for (int it = 0; it < nit; ++it) {
    // next tile (clamped to current for the last one -> tail stages are dummies)
    int vN = v + 256;
    int wgN = (it + 1 < nit) ? ((vN & 7) * cpx + (vN >> 3)) : wg;
    int bmN = wgN / nbx, bnN = wgN % nbx;
    const unsigned short* nxtA = A + (size_t)(bmN * 256 + aro) * K + scol;
    const unsigned short* nxtB = BT + (size_t)(bnN * 256 + bro) * K + scol;

#pragma unroll
    for (int i = 0; i < 8; i++)
#pragma unroll
      for (int j = 0; j < 4; j++) acc[i][j] = {0.f, 0.f, 0.f, 0.f};

    for (int t = 0; t < NT; ++t) {
      const int b = t & 1;
      const unsigned short *A1, *B1, *A2, *B2; int k1, k2;
      if (t + 1 < NT) { A1 = curA; B1 = curB; k1 = (t + 1) << 6; }
      else            { A1 = nxtA; B1 = nxtB; k1 = 0; }
      if (t + 2 < NT) { A2 = curA; B2 = curB; k2 = (t + 2) << 6; }
      else            { A2 = nxtA; B2 = nxtB; k2 = (t + 2 - NT) << 6; }

      // P0: read A-S0 (8) + B-S0 (4); stage B-S1(step t+1); MFMA (mh0,nh0)
#pragma unroll
      for (int mi = 0; mi < 4; mi++)
#pragma unroll
        for (int ks = 0; ks < 2; ks++)
          a[mi][ks] = *(const bf16x8*)&lds[b][0][0][(wm2 * 64 + mi * 16 + lm) * 64 + ((ks * 32 + quad * 8) ^ ex)];
#pragma unroll
      for (int ni = 0; ni < 2; ni++)
#pragma unroll
        for (int ks = 0; ks < 2; ks++)
          b0[ni][ks] = *(const bf16x8*)&lds[b][1][0][(wn4 * 32 + ni * 16 + lm) * 64 + ((ks * 32 + quad * 8) ^ ex)];
      stB(B1, b ^ 1, 1, k1);
      __builtin_amdgcn_s_barrier();
      __builtin_amdgcn_s_setprio(1);
#pragma unroll
      for (int ks = 0; ks < 2; ks++)
#pragma unroll
        for (int mi = 0; mi < 4; mi++)
#pragma unroll
          for (int ni = 0; ni < 2; ni++)
            acc[mi][ni] = __builtin_amdgcn_mfma_f32_16x16x32_bf16(a[mi][ks], b0[ni][ks], acc[mi][ni], 0, 0, 0);
      __builtin_amdgcn_s_setprio(0);
      __builtin_amdgcn_s_barrier();

      // P1: read B-S1 (4); stage A-S1(step t+1); MFMA (mh0,nh1)
#pragma unroll
      for (int ni = 0; ni < 2; ni++)
#pragma unroll
        for (int ks = 0; ks < 2; ks++)
          b1[ni][ks] = *(const bf16x8*)&lds[b][1][1][(wn4 * 32 + ni * 16 + lm) * 64 + ((ks * 32 + quad * 8) ^ ex)];
      stA(A1, b ^ 1, 1, k1);
      __builtin_amdgcn_s_barrier();
      __builtin_amdgcn_s_setprio(1);
#pragma unroll
      for (int ks = 0; ks < 2; ks++)
#pragma unroll
        for (int mi = 0; mi < 4; mi++)
#pragma unroll
          for (int ni = 0; ni < 2; ni++)
            acc[mi][2 + ni] = __builtin_amdgcn_mfma_f32_16x16x32_bf16(a[mi][ks], b1[ni][ks], acc[mi][2 + ni], 0, 0, 0);
      __builtin_amdgcn_s_setprio(0);
      __builtin_amdgcn_s_barrier();

      // P2: read A-S1 (8); stage A-S0(step t+2); MFMA (mh1,nh0) reusing b0
#pragma unroll
      for (int mi = 0; mi < 4; mi++)
#pragma unroll
        for (int ks = 0; ks < 2; ks++)
          a[mi][ks] = *(const bf16x8*)&lds[b][0][1][(wm2 * 64 + mi * 16 + lm) * 64 + ((ks * 32 + quad * 8) ^ ex)];
      stA(A2, b, 0, k2);
      __builtin_amdgcn_s_barrier();
      __builtin_amdgcn_s_setprio(1);
#pragma unroll
      for (int ks = 0; ks < 2; ks++)
#pragma unroll
        for (int mi = 0; mi < 4; mi++)
#pragma unroll
          for (int ni = 0; ni < 2; ni++)
            acc[4 + mi][ni] = __builtin_amdgcn_mfma_f32_16x16x32_bf16(a[mi][ks], b0[ni][ks], acc[4 + mi][ni], 0, 0, 0);
      __builtin_amdgcn_s_setprio(0);
      __builtin_amdgcn_s_barrier();

      // P3: no ds_read; stage B-S0(step t+2); MFMA (mh1,nh1) reusing a,b1
      stB(B2, b, 0, k2);
      __builtin_amdgcn_s_barrier();
      __builtin_amdgcn_s_setprio(1);
#pragma unroll
      for (int ks = 0; ks < 2; ks++)
#pragma unroll
        for (int mi = 0; mi < 4; mi++)
#pragma unroll
          for (int ni = 0; ni < 2; ni++)
            acc[4 + mi][2 + ni] = __builtin_amdgcn_mfma_f32_16x16x32_bf16(a[mi][ks], b1[ni][ks], acc[4 + mi][2 + ni], 0, 0, 0);
      __builtin_amdgcn_s_setprio(0);
      // single counted wait per K-step: completes step t+1's stages (issued
      // P0/P1), leaves step t+2's (P2/P3, newest 4) in flight.
      asm volatile("s_waitcnt vmcnt(4)" ::: "memory");
      __builtin_amdgcn_s_barrier();
    }

    // ---- epilogue for this tile (next tile's first stages already in flight)
    float bv[4];
#pragma unroll
    for (int jn = 0; jn < 4; jn++)
      bv[jn] = bias ? bias[bn * 256 + wn4 * 64 + jn * 16 + lm] : 0.f;
    const int rb = bm * 256 + wm2 * 128 + quad * 4;
    const int cb = bn * 256 + wn4 * 64 + lm;
#pragma unroll
    for (int im = 0; im < 8; im++)
#pragma unroll
      for (int jn = 0; jn < 4; jn++)
#pragma unroll
        for (int r = 0; r < 4; r++) {
          float vvv = acc[im][jn][r] + bv[jn];
          if (EPI == 1) {
            // gelu(x) = x * sigmoid(1.5957691*(x + 0.044715 x^3))
            // exp(-u) = exp2(-1.5957691*log2e * x*(1+0.044715 x^2))
            float xx = vvv;
            float x2 = xx * xx;
            float t = xx * fmaf(x2, 0.044715f, 1.0f);
            float e = exp2f(-2.3022083f * t);
            vvv = xx * __builtin_amdgcn_rcpf(1.f + e);
          }
          C[(size_t)(rb + im * 16 + r) * N + cb + jn * 16] = f2bf(vvv);
        }

    v = vN; wg = wgN; bm = bmN; bn = bnN; curA = nxtA; curB = nxtB;
  }
  // drain dummy tail stages before LDS is freed
  asm volatile("s_waitcnt vmcnt(0)" ::: "memory");
}

// ---------- weight transpose + cast: W[K,N] fp32 -> WT[N,K] bf16 ----------
__global__ __launch_bounds__(256) void transpose_cast(
    const float* __restrict__ W, unsigned short* __restrict__ WT, int K, int N)
{
  __shared__ float t[32][33];
  int bx = blockIdx.x, by = blockIdx.y;
  int tx = threadIdx.x & 31, ty = threadIdx.x >> 5;
#pragma unroll
  for (int j = 0; j < 4; j++)
    t[ty + j * 8][tx] = W[(size_t)(by * 32 + ty + j * 8) * N + bx * 32 + tx];
  __syncthreads();
#pragma unroll
  for (int j = 0; j < 4; j++)
    WT[(size_t)(bx * 32 + ty + j * 8) * K + by * 32 + tx] = f2bf(t[tx][ty + j * 8]);
}

// ---------- shift + window partition + cast ----------
__global__ __launch_bounds__(256) void shift_part(
    const float* __restrict__ x, unsigned short* __restrict__ xw)
{
  int t = blockIdx.x * 256 + threadIdx.x;
  int row = t >> 7;
  int c = (t & 127) * 4;
  int b = row >> 12, rw_ = row & 4095;
  int wi = rw_ >> 6, p = rw_ & 63;
  int hh = (((wi >> 3) * 8 + (p >> 3)) + 4) & 63;
  int ww = (((wi & 7) * 8 + (p & 7)) + 4) & 63;
  const float4 v = *(const float4*)&x[(((size_t)b * 4096) + hh * 64 + ww) * 512 + c];
  ushort4 o;
  o.x = f2bf(v.x); o.y = f2bf(v.y); o.z = f2bf(v.z); o.w = f2bf(v.w);
  *(ushort4*)&xw[(size_t)row * 512 + c] = o;
}

// ---------- assemble fused QKV bias: [q_b | 0 | v_b] ----------
__global__ __launch_bounds__(256) void qkv_bias_kernel(
    const float* __restrict__ qb, const float* __restrict__ vb, float* __restrict__ o)
{
  int t = blockIdx.x * 256 + threadIdx.x;   // 0..1535
  float v = 0.f;
  if (t < 512) v = qb[t];
  else if (t >= 1024) v = vb[t - 1024];
  o[t] = v;
}

// ---------- CPB table: tblT[16][225] fp32, PRE-SIGMOIDED: 16*sigmoid(mlp(rel)) ----------
__device__ __forceinline__ float relsc(int v) {
  float a = fabsf((float)v) * (8.0f / 7.0f);
  float r = log2f(a + 1.f) * (1.f / 3.f);
  return v < 0 ? -r : r;
}
__global__ __launch_bounds__(512) void cpb_kernel(
    const float* __restrict__ w1, const float* __restrict__ b1,
    const float* __restrict__ w2, const float* __restrict__ b2, float* __restrict__ tblT)
{
  __shared__ float hid[512];
  int p = blockIdx.x;
  int i = p / 15, j = p % 15;
  float fr = relsc(i - 7);
  float fc = relsc(j - 7);
  int t = threadIdx.x;
  float hv = fc * w1[t] + fr * w1[512 + t] + b1[t];
  hid[t] = fmaxf(hv, 0.f);
  __syncthreads();
  if (t < 16) {
    float s = b2[t];
    for (int u = 0; u < 512; u++) s += hid[u] * w2[u * 16 + t];
    tblT[t * 225 + p] = 16.f / (1.f + __expf(-s));   // fold sigmoid here
  }
}

// ---------- MFMA attention: one block per (window, head-octet), 4 waves ----------
__global__ __launch_bounds__(256) void attn_mfma(
    const unsigned short* __restrict__ QKV, const float* __restrict__ tau,
    const float* __restrict__ tblT, unsigned short* __restrict__ Om)
{
  __shared__ __align__(16) unsigned short Qs[64 * 32];
  __shared__ __align__(16) unsigned short Ks[64 * 32];
  __shared__ __align__(16) unsigned short Vs[64 * 32];
  __shared__ __align__(16) unsigned short VT[32 * 72];   // V^T, stride 72
  __shared__ __align__(16) unsigned short Pb[64 * 72];   // P, stride 72
  __shared__ float tblh[2][228];
  __shared__ int scode[64];

  const int tid = threadIdx.x;
  const int wave = tid >> 6, lane = tid & 63;
  const int lm = lane & 15, quad = lane >> 4;
  const int w = blockIdx.x >> 1;                   // window 0..1023
  const int hbase = (blockIdx.x & 1) * 8;          // heads [hbase, hbase+8)
  const int wi = w & 63, wr = wi >> 3, wc = wi & 7;
  const size_t wbase = (size_t)w * 64 * 1536;
  const size_t obase = (size_t)w * 64 * 512;

  if (tid < 64) {
    int p = tid;
    int rp = wr * 8 + (p >> 3), cp = wc * 8 + (p & 7);
    scode[p] = (rp < 56 ? 0 : (rp < 60 ? 1 : 2)) * 3 + (cp < 56 ? 0 : (cp < 60 ? 1 : 2));
  }

  const int srow = wave * 16 + (lane >> 2);
  const int scol = (lane & 3) * 8;
  unsigned short* qdst = &Qs[wave * 16 * 32];
  unsigned short* kdst = &Ks[wave * 16 * 32];
  unsigned short* vdst = &Vs[wave * 16 * 32];
  const size_t gs0 = wbase + (size_t)srow * 1536 + scol;

  {
    const size_t g = gs0 + (size_t)hbase * 32;
    g2lds16(QKV + g, qdst);
    g2lds16(QKV + g + 512, kdst);
    g2lds16(QKV + g + 1024, vdst);
    for (int e = tid; e < 225; e += 256) tblh[0][e] = tblT[hbase * 225 + e];
  }

  for (int hh = 0; hh < 8; hh++) {
    const int h = hbase + hh, cur = hh & 1;
    __syncthreads();   // A: staging + tblh[cur] visible; prev head's consumers done

    u16x8 au = *(const u16x8*)&Qs[(wave * 16 + lm) * 32 + quad * 8];
    float qss = 0.f;
#pragma unroll
    for (int j = 0; j < 8; j++) { float f = bf2f(au[j]); qss += f * f; }
    qss += __shfl_xor(qss, 16, 64);
    qss += __shfl_xor(qss, 32, 64);
    const float qnv = sqrtf(qss);

    u16x8 bu[4]; float knv[4];
#pragma unroll
    for (int ni = 0; ni < 4; ni++) {
      bu[ni] = *(const u16x8*)&Ks[(ni * 16 + lm) * 32 + quad * 8];
      float kss = 0.f;
#pragma unroll
      for (int j = 0; j < 8; j++) { float f = bf2f(bu[ni][j]); kss += f * f; }
      kss += __shfl_xor(kss, 16, 64);
      kss += __shfl_xor(kss, 32, 64);
      knv[ni] = sqrtf(kss);
    }

    bf16x8 af = as_bf(au);
    f32x4 accS[4];
#pragma unroll
    for (int ni = 0; ni < 4; ni++) {
      f32x4 z = {0.f, 0.f, 0.f, 0.f};
      accS[ni] = __builtin_amdgcn_mfma_f32_16x16x32_bf16(af, as_bf(bu[ni]), z, 0, 0, 0);
    }

    for (int e = tid; e < 2048; e += 256) {
      int d = e & 31, q = e >> 5;
      VT[d * 72 + q] = Vs[q * 32 + d];
    }

    const float scale = fmaxf(tau[h] + 2.302585092994046f, 0.01f);
#pragma unroll
    for (int r = 0; r < 4; r++) {
      int p = wave * 16 + quad * 4 + r;
      float qnp = __shfl(qnv, quad * 4 + r, 64);
      int cp = scode[p];
      float sv[4];
#pragma unroll
      for (int ni = 0; ni < 4; ni++) {
        int q = ni * 16 + lm;
        float denom = fmaxf(qnp * knv[ni], 1e-6f);
        int dr = (p >> 3) - (q >> 3) + 7, dc = (p & 7) - (q & 7) + 7;
        float bv = tblh[cur][dr * 15 + dc];
        float mask = (cp == scode[q]) ? 0.f : -100.f;
        sv[ni] = accS[ni][r] * scale * __builtin_amdgcn_rcpf(denom) + bv + mask;
      }
      float m = fmaxf(fmaxf(sv[0], sv[1]), fmaxf(sv[2], sv[3]));
#pragma unroll
      for (int off = 1; off < 16; off <<= 1) m = fmaxf(m, __shfl_xor(m, off, 64));
      float s = 0.f;
#pragma unroll
      for (int ni = 0; ni < 4; ni++) { sv[ni] = __expf(sv[ni] - m); s += sv[ni]; }
#pragma unroll
      for (int off = 1; off < 16; off <<= 1) s += __shfl_xor(s, off, 64);
      float inv = __builtin_amdgcn_rcpf(s);
#pragma unroll
      for (int ni = 0; ni < 4; ni++)
        Pb[p * 72 + ni * 16 + lm] = f2bf(sv[ni] * inv);
    }

    __syncthreads();   // B: VT complete; all reads of Qs/Ks/Vs done

    if (hh < 7) {
      const size_t g = gs0 + (size_t)(h + 1) * 32;
      g2lds16(QKV + g, qdst);
      g2lds16(QKV + g + 512, kdst);
      g2lds16(QKV + g + 1024, vdst);
      for (int e = tid; e < 225; e += 256) tblh[cur ^ 1][e] = tblT[(h + 1) * 225 + e];
    }

    bf16x8 paf[2];
#pragma unroll
    for (int kc = 0; kc < 2; kc++)
      paf[kc] = *reinterpret_cast<const bf16x8*>(&Pb[(wave * 16 + lm) * 72 + kc * 32 + quad * 8]);
    f32x4 accO[2];
#pragma unroll
    for (int n2 = 0; n2 < 2; n2++) {
      f32x4 z = {0.f, 0.f, 0.f, 0.f};
#pragma unroll
      for (int kc = 0; kc < 2; kc++) {
        bf16x8 vb = *reinterpret_cast<const bf16x8*>(&VT[(n2 * 16 + lm) * 72 + kc * 32 + quad * 8]);
        z = __builtin_amdgcn_mfma_f32_16x16x32_bf16(paf[kc], vb, z, 0, 0, 0);
      }
      accO[n2] = z;
    }
#pragma unroll
    for (int n2 = 0; n2 < 2; n2++)
#pragma unroll
      for (int r = 0; r < 4; r++) {
        int p = wave * 16 + quad * 4 + r;
        Om[obase + (size_t)p * 512 + h * 32 + n2 * 16 + lm] = f2bf(accO[n2][r]);
      }
  }
}

// ---------- LN1: wave-per-token un-shift gather + layernorm + residual -> x1 bf16 ----------
__global__ __launch_bounds__(256) void ln1_kernel(
    const float* __restrict__ x, const unsigned short* __restrict__ proj,
    const float* __restrict__ g, const float* __restrict__ b,
    unsigned short* __restrict__ x1b)
{
  int tkn = blockIdx.x * 4 + (threadIdx.x >> 6);
  int lane = threadIdx.x & 63;
  int bb = tkn >> 12, s = tkn & 4095;
  int h_ = s >> 6, w_ = s & 63;
  int r = (h_ + 60) & 63, cc = (w_ + 60) & 63;
  int wi = (r >> 3) * 8 + (cc >> 3);
  int p = (r & 7) * 8 + (cc & 7);
  size_t src = ((size_t)bb * 4096 + wi * 64 + p) * 512 + lane * 8;
  u16x8 pv = *(const u16x8*)&proj[src];
  float v[8]; float ls = 0.f, lq = 0.f;
#pragma unroll
  for (int j = 0; j < 8; j++) { v[j] = bf2f(pv[j]); ls += v[j]; lq += v[j] * v[j]; }
#pragma unroll
  for (int off = 1; off < 64; off <<= 1) {
    ls += __shfl_xor(ls, off, 64);
    lq += __shfl_xor(lq, off, 64);
  }
  float mean = ls * (1.f / 512.f);
  float rstd = rsqrtf(lq * (1.f / 512.f) - mean * mean + 1e-6f);
  int c = lane * 8;
  size_t o = (size_t)tkn * 512 + c;
  float4 xa = *(const float4*)&x[o], xb = *(const float4*)&x[o + 4];
  float4 ga = *(const float4*)&g[c], gb = *(const float4*)&g[c + 4];
  float4 ba = *(const float4*)&b[c], bb4 = *(const float4*)&b[c + 4];
  u16x8 ov;
  ov[0] = f2bf((v[0] - mean) * rstd * ga.x + ba.x + xa.x);
  ov[1] = f2bf((v[1] - mean) * rstd * ga.y + ba.y + xa.y);
  ov[2] = f2bf((v[2] - mean) * rstd * ga.z + ba.z + xa.z);
  ov[3] = f2bf((v[3] - mean) * rstd * ga.w + ba.w + xa.w);
  ov[4] = f2bf((v[4] - mean) * rstd * gb.x + bb4.x + xb.x);
  ov[5] = f2bf((v[5] - mean) * rstd * gb.y + bb4.y + xb.y);
  ov[6] = f2bf((v[6] - mean) * rstd * gb.z + bb4.z + xb.z);
  ov[7] = f2bf((v[7] - mean) * rstd * gb.w + bb4.w + xb.w);
  *(u16x8*)&x1b[o] = ov;
}

// ---------- LN2 + residual -> out fp32 (wave-per-token) ----------
__global__ __launch_bounds__(256) void ln2_kernel(
    const unsigned short* __restrict__ x1b, const unsigned short* __restrict__ h2,
    const float* __restrict__ g, const float* __restrict__ b,
    float* __restrict__ out)
{
  int tkn = blockIdx.x * 4 + (threadIdx.x >> 6);
  int lane = threadIdx.x & 63;
  int c = lane * 8;
  size_t o = (size_t)tkn * 512 + c;
  u16x8 hv = *(const u16x8*)&h2[o];
  float v[8]; float ls = 0.f, lq = 0.f;
#pragma unroll
  for (int j = 0; j < 8; j++) { v[j] = bf2f(hv[j]); ls += v[j]; lq += v[j] * v[j]; }
#pragma unroll
  for (int off = 1; off < 64; off <<= 1) {
    ls += __shfl_xor(ls, off, 64);
    lq += __shfl_xor(lq, off, 64);
  }
  float mean = ls * (1.f / 512.f);
  float rstd = rsqrtf(lq * (1.f / 512.f) - mean * mean + 1e-6f);
  u16x8 xv = *(const u16x8*)&x1b[o];
  float4 ga = *(const float4*)&g[c], gb = *(const float4*)&g[c + 4];
  float4 ba = *(const float4*)&b[c], bb4 = *(const float4*)&b[c + 4];
  float4 oa, ob;
  oa.x = bf2f(xv[0]) + (v[0] - mean) * rstd * ga.x + ba.x;
  oa.y = bf2f(xv[1]) + (v[1] - mean) * rstd * ga.y + ba.y;
  oa.z = bf2f(xv[2]) + (v[2] - mean) * rstd * ga.z + ba.z;
  oa.w = bf2f(xv[3]) + (v[3] - mean) * rstd * ga.w + ba.w;
  ob.x = bf2f(xv[4]) + (v[4] - mean) * rstd * gb.x + bb4.x;
  ob.y = bf2f(xv[5]) + (v[5] - mean) * rstd * gb.y + bb4.y;
  ob.z = bf2f(xv[6]) + (v[6] - mean) * rstd * gb.z + bb4.z;
  ob.w = bf2f(xv[7]) + (v[7] - mean) * rstd * gb.w + bb4.w;
  *(float4*)&out[o] = oa;
  *(float4*)&out[o + 4] = ob;
}

// ---------- launcher ----------
extern "C" void kernel_launch(void* const* d_in, const int* in_sizes, int n_in,
                              void* d_out, int out_size, void* d_ws, size_t ws_size,
                              hipStream_t stream) {
  const float* x      = (const float*)d_in[0];
  const float* q_w    = (const float*)d_in[1];
  const float* q_b    = (const float*)d_in[2];
  const float* k_w    = (const float*)d_in[3];
  const float* v_w    = (const float*)d_in[4];
  const float* v_b    = (const float*)d_in[5];
  const float* proj_w = (const float*)d_in[6];
  const float* proj_b = (const float*)d_in[7];
  const float* tau    = (const float*)d_in[8];
  const float* cpb_w1 = (const float*)d_in[9];
  const float* cpb_b1 = (const float*)d_in[10];
  const float* cpb_w2 = (const float*)d_in[11];
  const float* cpb_b2 = (const float*)d_in[12];
  const float* n1g    = (const float*)d_in[13];
  const float* n1b    = (const float*)d_in[14];
  const float* n2g    = (const float*)d_in[15];
  const float* n2b    = (const float*)d_in[16];
  const float* mlp_w1 = (const float*)d_in[17];
  const float* mlp_b1 = (const float*)d_in[18];
  const float* mlp_w2 = (const float*)d_in[19];
  const float* mlp_b2 = (const float*)d_in[20];
  float* out = (float*)d_out;
  char* ws = (char*)d_ws;

  const size_t MB = 1048576;
  unsigned short* xw    = (unsigned short*)(ws + 0 * MB);
  unsigned short* Obuf  = (unsigned short*)(ws + 0 * MB);
  unsigned short* hbuf  = (unsigned short*)(ws + 0 * MB);
  unsigned short* qkv   = (unsigned short*)(ws + 64 * MB);
  unsigned short* projb = (unsigned short*)(ws + 64 * MB);
  unsigned short* x1b   = (unsigned short*)(ws + 128 * MB);
  unsigned short* h2b   = (unsigned short*)(ws + 192 * MB);
  unsigned short* qkvT = (unsigned short*)(ws + 320 * MB);
  unsigned short* pwT  = (unsigned short*)(ws + 320 * MB + 1572864);
  unsigned short* m1T  = (unsigned short*)(ws + 320 * MB + 2097152);
  unsigned short* m2T  = (unsigned short*)(ws + 320 * MB + 4194304);
  float* tbl           = (float*)         (ws + 320 * MB + 6291456);   // 16x225 f32
  float* qkv_b         = (float*)         (ws + 320 * MB + 6307840);

  transpose_cast<<<dim3(16, 16), 256, 0, stream>>>(q_w,    qkvT,          512, 512);
  transpose_cast<<<dim3(16, 16), 256, 0, stream>>>(k_w,    qkvT + 262144, 512, 512);
  transpose_cast<<<dim3(16, 16), 256, 0, stream>>>(v_w,    qkvT + 524288, 512, 512);
  transpose_cast<<<dim3(16, 16), 256, 0, stream>>>(proj_w, pwT, 512, 512);
  transpose_cast<<<dim3(64, 16), 256, 0, stream>>>(mlp_w1, m1T, 512, 2048);
  transpose_cast<<<dim3(16, 64), 256, 0, stream>>>(mlp_w2, m2T, 2048, 512);
  qkv_bias_kernel<<<6, 256, 0, stream>>>(q_b, v_b, qkv_b);
  cpb_kernel<<<225, 512, 0, stream>>>(cpb_w1, cpb_b1, cpb_w2, cpb_b2, tbl);
  shift_part<<<32768, 256, 0, stream>>>(x, xw);
  // fused QKV: [65536,512] x [512,1536]; T = 256*6 = 1536 tiles
  gemm256<0><<<256, 512, 0, stream>>>(xw, qkvT, qkv_b, qkv, 1536, 512, 6, 1536);
  attn_mfma<<<2048, 256, 0, stream>>>(qkv, tau, tbl, Obuf);
  gemm256<0><<<256, 512, 0, stream>>>(Obuf, pwT, proj_b, projb, 512, 512, 2, 512);
  ln1_kernel<<<16384, 256, 0, stream>>>(x, projb, n1g, n1b, x1b);
  for (int c2 = 0; c2 < 2; c2++) {
    const unsigned short* a = x1b + (size_t)c2 * 32768 * 512;
    unsigned short* h2p = h2b + (size_t)c2 * 32768 * 512;
    gemm256<1><<<256, 512, 0, stream>>>(a, m1T, mlp_b1, hbuf, 2048, 512, 8, 1024);
    gemm256<0><<<256, 512, 0, stream>>>(hbuf, m2T, mlp_b2, h2p, 512, 2048, 2, 256);
  }
  ln2_kernel<<<16384, 256, 0, stream>>>(x1b, h2b, n2g, n2b, out);
}

// Round 7
// 901.510 us; speedup vs baseline: 1.0456x; 1.0456x over previous
//
#include <hip/hip_runtime.h>
#include <cstdint>
#include <cstddef>

// I/O fp32; intermediates bf16; math fp32.
typedef __bf16 bf16x8 __attribute__((ext_vector_type(8)));
typedef float  f32x4  __attribute__((ext_vector_type(4)));
typedef unsigned short u16x8 __attribute__((ext_vector_type(8)));

__device__ __forceinline__ float bf2f(unsigned short u) {
  union { unsigned int u; float f; } v; v.u = ((unsigned int)u) << 16; return v.f;
}
__device__ __forceinline__ unsigned short f2bf(float f) {
  union { float f; unsigned int u; } v; v.f = f;
  return (unsigned short)((v.u + 0x7fffu + ((v.u >> 16) & 1u)) >> 16);
}
__device__ __forceinline__ bf16x8 as_bf(u16x8 u) {
  union { u16x8 a; bf16x8 b; } v; v.a = u; return v.b;
}
__device__ __forceinline__ void g2lds16(const void* g, void* l) {
  __builtin_amdgcn_global_load_lds((__attribute__((address_space(1))) void*)g,
                                   (__attribute__((address_space(3))) void*)l,
                                   16, 0, 0);
}

// ---------- persistent 256x256 deep-pipelined GEMM, 2 barriers / K-step ----------
// grid = 256 blocks; flat cross-tile pipeline (tail stages of tile i are the
// prologue of tile i+1; NT even keeps buffer parity). 8 waves (2M x 4N), BK=64,
// 2 LDS bufs (128 KiB).
// Region1: all 24 ds_reads (interleaved with MFMA q0,q1,q2 so counted lgkmcnt
//   overlaps LDS pipe with matrix pipe) + early stages S1(t+1) -> OTHER buffer
//   (reads of it finished a full step ago: unconditionally WAR-safe).
// BARRIER: every wave has ISSUED its reads of buf b (LDS reads execute ~120cy
//   after issue) before any late write to buf b is issued (lands >=200cy after
//   issue) -> ordered with margin. [R6's 0-barrier variant raced here.]
// Region2: late stages S0(t+2) -> CURRENT buffer + q3 + single counted
//   vmcnt(4) + barrier. EPI: 0=+bias, 1=+bias+gelu(exp2+rcp).
template<int EPI>
__global__ __launch_bounds__(512, 2) void gemm256(
    const unsigned short* __restrict__ A, const unsigned short* __restrict__ BT,
    const float* __restrict__ bias, unsigned short* __restrict__ C,
    int N, int K, int nbx, int T)
{
  __shared__ __align__(16) unsigned short lds[2][2][2][128 * 64];  // [buf][A/B][Shalf][128x64]
  const int tid = threadIdx.x;
  const int wave = tid >> 6, lane = tid & 63;
  const int lm = lane & 15, quad = lane >> 4;
  const int wm2 = wave >> 2, wn4 = wave & 3;
  const int ex = (lm & 7) << 3;   // read-side swizzle xor (elems)

  const int NT = K >> 6;
  const int cpx = T >> 3;
  const int nit = T >> 8;         // tiles per block (grid = 256)

  const int sl8 = lane >> 3;
  const int scol = ((lane & 7) ^ sl8) << 3;       // inverse-swizzled source col (elems)
  const int r0 = wave * 8 + sl8;                  // 0..63
  const int aro = r0;                              // A region row
  const int bro = (r0 >> 5) * 64 + (r0 & 31);      // B region row

  auto stA = [&](const unsigned short* Ab, int bf, int sh, int koff) {
    const unsigned short* s = Ab + (size_t)(sh * 64) * K + koff;
    g2lds16(s,                   &lds[bf][0][sh][wave * 512]);
    g2lds16(s + (size_t)128 * K, &lds[bf][0][sh][4096 + wave * 512]);
  };
  auto stB = [&](const unsigned short* Bb, int bf, int sh, int koff) {
    const unsigned short* s = Bb + (size_t)(sh * 32) * K + koff;
    g2lds16(s,                   &lds[bf][1][sh][wave * 512]);
    g2lds16(s + (size_t)128 * K, &lds[bf][1][sh][4096 + wave * 512]);
  };

  // tile 0
  int v = blockIdx.x;
  int wg = (v & 7) * cpx + (v >> 3);
  int bm = wg / nbx, bn = wg % nbx;
  const unsigned short* curA = A + (size_t)(bm * 256 + aro) * K + scol;
  const unsigned short* curB = BT + (size_t)(bn * 256 + bro) * K + scol;

  f32x4 acc[8][4];
  bf16x8 a[4][2], b0[2][2], b1[2][2];

  // ---- prologue: S0(0), S1(0) complete; S0(1) in flight
  stA(curA, 0, 0, 0); stB(curB, 0, 0, 0);
  stB(curB, 0, 1, 0); stA(curA, 0, 1, 0);
  stA(curA, 1, 0, 64); stB(curB, 1, 0, 64);
  asm volatile("s_waitcnt vmcnt(4)" ::: "memory");
  __builtin_amdgcn_s_barrier();

  for (int it = 0; it < nit; ++it) {
    // next tile (clamped to current for the last one -> tail stages are dummies)
    int vN = v + 256;
    int wgN = (it + 1 < nit) ? ((vN & 7) * cpx + (vN >> 3)) : wg;
    int bmN = wgN / nbx, bnN = wgN % nbx;
    const unsigned short* nxtA = A + (size_t)(bmN * 256 + aro) * K + scol;
    const unsigned short* nxtB = BT + (size_t)(bnN * 256 + bro) * K + scol;

#pragma unroll
    for (int i = 0; i < 8; i++)
#pragma unroll
      for (int j = 0; j < 4; j++) acc[i][j] = {0.f, 0.f, 0.f, 0.f};

    for (int t = 0; t < NT; ++t) {
      const int b = t & 1;
      const unsigned short *A1, *B1, *A2, *B2; int k1, k2;
      if (t + 1 < NT) { A1 = curA; B1 = curB; k1 = (t + 1) << 6; }
      else            { A1 = nxtA; B1 = nxtB; k1 = 0; }
      if (t + 2 < NT) { A2 = curA; B2 = curB; k2 = (t + 2) << 6; }
      else            { A2 = nxtA; B2 = nxtB; k2 = (t + 2 - NT) << 6; }

      // ================= REGION 1 =================
      // reads: a-S0 (8) + b-S0 (4)
#pragma unroll
      for (int mi = 0; mi < 4; mi++)
#pragma unroll
        for (int ks = 0; ks < 2; ks++)
          a[mi][ks] = *(const bf16x8*)&lds[b][0][0][(wm2 * 64 + mi * 16 + lm) * 64 + ((ks * 32 + quad * 8) ^ ex)];
#pragma unroll
      for (int ni = 0; ni < 2; ni++)
#pragma unroll
        for (int ks = 0; ks < 2; ks++)
          b0[ni][ks] = *(const bf16x8*)&lds[b][1][0][(wn4 * 32 + ni * 16 + lm) * 64 + ((ks * 32 + quad * 8) ^ ex)];
      // early stages: S1(t+1) into the OTHER buffer (WAR-safe: its reads ended
      // in step t-1, a barrier ago)
      stB(B1, b ^ 1, 1, k1);
      stA(A1, b ^ 1, 1, k1);

      // q0: (mh0, nh0)
      __builtin_amdgcn_s_setprio(1);
#pragma unroll
      for (int ks = 0; ks < 2; ks++)
#pragma unroll
        for (int mi = 0; mi < 4; mi++)
#pragma unroll
          for (int ni = 0; ni < 2; ni++)
            acc[mi][ni] = __builtin_amdgcn_mfma_f32_16x16x32_bf16(a[mi][ks], b0[ni][ks], acc[mi][ni], 0, 0, 0);
      __builtin_amdgcn_s_setprio(0);

      // reads: b-S1 (4)
#pragma unroll
      for (int ni = 0; ni < 2; ni++)
#pragma unroll
        for (int ks = 0; ks < 2; ks++)
          b1[ni][ks] = *(const bf16x8*)&lds[b][1][1][(wn4 * 32 + ni * 16 + lm) * 64 + ((ks * 32 + quad * 8) ^ ex)];

      // q1: (mh0, nh1)
      __builtin_amdgcn_s_setprio(1);
#pragma unroll
      for (int ks = 0; ks < 2; ks++)
#pragma unroll
        for (int mi = 0; mi < 4; mi++)
#pragma unroll
          for (int ni = 0; ni < 2; ni++)
            acc[mi][2 + ni] = __builtin_amdgcn_mfma_f32_16x16x32_bf16(a[mi][ks], b1[ni][ks], acc[mi][2 + ni], 0, 0, 0);
      __builtin_amdgcn_s_setprio(0);

      // reads: a-S1 (8), reusing a[]
#pragma unroll
      for (int mi = 0; mi < 4; mi++)
#pragma unroll
        for (int ks = 0; ks < 2; ks++)
          a[mi][ks] = *(const bf16x8*)&lds[b][0][1][(wm2 * 64 + mi * 16 + lm) * 64 + ((ks * 32 + quad * 8) ^ ex)];

      // q2: (mh1, nh0)
      __builtin_amdgcn_s_setprio(1);
#pragma unroll
      for (int ks = 0; ks < 2; ks++)
#pragma unroll
        for (int mi = 0; mi < 4; mi++)
#pragma unroll
          for (int ni = 0; ni < 2; ni++)
            acc[4 + mi][ni] = __builtin_amdgcn_mfma_f32_16x16x32_bf16(a[mi][ks], b0[ni][ks], acc[4 + mi][ni], 0, 0, 0);
      __builtin_amdgcn_s_setprio(0);

      // all reads of buf b issued by every wave before any late write to buf b
      __builtin_amdgcn_s_barrier();

      // ================= REGION 2 =================
      // late stages: S0(t+2) into THIS buffer (reads issued pre-barrier,
      // execute ~120cy after issue; these writes land >=200cy after issue)
      stA(A2, b, 0, k2);
      stB(B2, b, 0, k2);

      // q3: (mh1, nh1)
      __builtin_amdgcn_s_setprio(1);
#pragma unroll
      for (int ks = 0; ks < 2; ks++)
#pragma unroll
        for (int mi = 0; mi < 4; mi++)
#pragma unroll
          for (int ni = 0; ni < 2; ni++)
            acc[4 + mi][2 + ni] = __builtin_amdgcn_mfma_f32_16x16x32_bf16(a[mi][ks], b1[ni][ks], acc[4 + mi][2 + ni], 0, 0, 0);
      __builtin_amdgcn_s_setprio(0);

      // single counted wait: completes S0(t+1) [late of t-1] and S1(t+1)
      // [early of t]; leaves this step's late 4 (S0(t+2)) in flight.
      asm volatile("s_waitcnt vmcnt(4)" ::: "memory");
      __builtin_amdgcn_s_barrier();
    }

    // ---- epilogue for this tile (next tile's first stages already in flight)
    float bv[4];
#pragma unroll
    for (int jn = 0; jn < 4; jn++)
      bv[jn] = bias ? bias[bn * 256 + wn4 * 64 + jn * 16 + lm] : 0.f;
    const int rb = bm * 256 + wm2 * 128 + quad * 4;
    const int cb = bn * 256 + wn4 * 64 + lm;
#pragma unroll
    for (int im = 0; im < 8; im++)
#pragma unroll
      for (int jn = 0; jn < 4; jn++)
#pragma unroll
        for (int r = 0; r < 4; r++) {
          float vvv = acc[im][jn][r] + bv[jn];
          if (EPI == 1) {
            float xx = vvv;
            float x2 = xx * xx;
            float tg = xx * fmaf(x2, 0.044715f, 1.0f);
            float e = exp2f(-2.3022083f * tg);
            vvv = xx * __builtin_amdgcn_rcpf(1.f + e);
          }
          C[(size_t)(rb + im * 16 + r) * N + cb + jn * 16] = f2bf(vvv);
        }

    v = vN; wg = wgN; bm = bmN; bn = bnN; curA = nxtA; curB = nxtB;
  }
  // drain dummy tail stages before LDS is freed
  asm volatile("s_waitcnt vmcnt(0)" ::: "memory");
}

// ---------- weight transpose + cast: W[K,N] fp32 -> WT[N,K] bf16 ----------
__global__ __launch_bounds__(256) void transpose_cast(
    const float* __restrict__ W, unsigned short* __restrict__ WT, int K, int N)
{
  __shared__ float t[32][33];
  int bx = blockIdx.x, by = blockIdx.y;
  int tx = threadIdx.x & 31, ty = threadIdx.x >> 5;
#pragma unroll
  for (int j = 0; j < 4; j++)
    t[ty + j * 8][tx] = W[(size_t)(by * 32 + ty + j * 8) * N + bx * 32 + tx];
  __syncthreads();
#pragma unroll
  for (int j = 0; j < 4; j++)
    WT[(size_t)(bx * 32 + ty + j * 8) * K + by * 32 + tx] = f2bf(t[tx][ty + j * 8]);
}

// ---------- shift + window partition + cast ----------
__global__ __launch_bounds__(256) void shift_part(
    const float* __restrict__ x, unsigned short* __restrict__ xw)
{
  int t = blockIdx.x * 256 + threadIdx.x;
  int row = t >> 7;
  int c = (t & 127) * 4;
  int b = row >> 12, rw_ = row & 4095;
  int wi = rw_ >> 6, p = rw_ & 63;
  int hh = (((wi >> 3) * 8 + (p >> 3)) + 4) & 63;
  int ww = (((wi & 7) * 8 + (p & 7)) + 4) & 63;
  const float4 v = *(const float4*)&x[(((size_t)b * 4096) + hh * 64 + ww) * 512 + c];
  ushort4 o;
  o.x = f2bf(v.x); o.y = f2bf(v.y); o.z = f2bf(v.z); o.w = f2bf(v.w);
  *(ushort4*)&xw[(size_t)row * 512 + c] = o;
}

// ---------- assemble fused QKV bias: [q_b | 0 | v_b] ----------
__global__ __launch_bounds__(256) void qkv_bias_kernel(
    const float* __restrict__ qb, const float* __restrict__ vb, float* __restrict__ o)
{
  int t = blockIdx.x * 256 + threadIdx.x;   // 0..1535
  float v = 0.f;
  if (t < 512) v = qb[t];
  else if (t >= 1024) v = vb[t - 1024];
  o[t] = v;
}

// ---------- CPB table: tblT[16][225] fp32, PRE-SIGMOIDED: 16*sigmoid(mlp(rel)) ----------
__device__ __forceinline__ float relsc(int v) {
  float a = fabsf((float)v) * (8.0f / 7.0f);
  float r = log2f(a + 1.f) * (1.f / 3.f);
  return v < 0 ? -r : r;
}
__global__ __launch_bounds__(512) void cpb_kernel(
    const float* __restrict__ w1, const float* __restrict__ b1,
    const float* __restrict__ w2, const float* __restrict__ b2, float* __restrict__ tblT)
{
  __shared__ float hid[512];
  int p = blockIdx.x;
  int i = p / 15, j = p % 15;
  float fr = relsc(i - 7);
  float fc = relsc(j - 7);
  int t = threadIdx.x;
  float hv = fc * w1[t] + fr * w1[512 + t] + b1[t];
  hid[t] = fmaxf(hv, 0.f);
  __syncthreads();
  if (t < 16) {
    float s = b2[t];
    for (int u = 0; u < 512; u++) s += hid[u] * w2[u * 16 + t];
    tblT[t * 225 + p] = 16.f / (1.f + __expf(-s));   // fold sigmoid here
  }
}

// ---------- MFMA attention: one block per (window, head-octet), 4 waves ----------
__global__ __launch_bounds__(256) void attn_mfma(
    const unsigned short* __restrict__ QKV, const float* __restrict__ tau,
    const float* __restrict__ tblT, unsigned short* __restrict__ Om)
{
  __shared__ __align__(16) unsigned short Qs[64 * 32];
  __shared__ __align__(16) unsigned short Ks[64 * 32];
  __shared__ __align__(16) unsigned short Vs[64 * 32];
  __shared__ __align__(16) unsigned short VT[32 * 72];   // V^T, stride 72
  __shared__ __align__(16) unsigned short Pb[64 * 72];   // P, stride 72
  __shared__ float tblh[2][228];
  __shared__ int scode[64];

  const int tid = threadIdx.x;
  const int wave = tid >> 6, lane = tid & 63;
  const int lm = lane & 15, quad = lane >> 4;
  const int w = blockIdx.x >> 1;                   // window 0..1023
  const int hbase = (blockIdx.x & 1) * 8;          // heads [hbase, hbase+8)
  const int wi = w & 63, wr = wi >> 3, wc = wi & 7;
  const size_t wbase = (size_t)w * 64 * 1536;
  const size_t obase = (size_t)w * 64 * 512;

  if (tid < 64) {
    int p = tid;
    int rp = wr * 8 + (p >> 3), cp = wc * 8 + (p & 7);
    scode[p] = (rp < 56 ? 0 : (rp < 60 ? 1 : 2)) * 3 + (cp < 56 ? 0 : (cp < 60 ? 1 : 2));
  }

  const int srow = wave * 16 + (lane >> 2);
  const int scol = (lane & 3) * 8;
  unsigned short* qdst = &Qs[wave * 16 * 32];
  unsigned short* kdst = &Ks[wave * 16 * 32];
  unsigned short* vdst = &Vs[wave * 16 * 32];
  const size_t gs0 = wbase + (size_t)srow * 1536 + scol;

  {
    const size_t g = gs0 + (size_t)hbase * 32;
    g2lds16(QKV + g, qdst);
    g2lds16(QKV + g + 512, kdst);
    g2lds16(QKV + g + 1024, vdst);
    for (int e = tid; e < 225; e += 256) tblh[0][e] = tblT[hbase * 225 + e];
  }

  for (int hh = 0; hh < 8; hh++) {
    const int h = hbase + hh, cur = hh & 1;
    __syncthreads();   // A: staging + tblh[cur] visible; prev head's consumers done

    u16x8 au = *(const u16x8*)&Qs[(wave * 16 + lm) * 32 + quad * 8];
    float qss = 0.f;
#pragma unroll
    for (int j = 0; j < 8; j++) { float f = bf2f(au[j]); qss += f * f; }
    qss += __shfl_xor(qss, 16, 64);
    qss += __shfl_xor(qss, 32, 64);
    const float qnv = sqrtf(qss);

    u16x8 bu[4]; float knv[4];
#pragma unroll
    for (int ni = 0; ni < 4; ni++) {
      bu[ni] = *(const u16x8*)&Ks[(ni * 16 + lm) * 32 + quad * 8];
      float kss = 0.f;
#pragma unroll
      for (int j = 0; j < 8; j++) { float f = bf2f(bu[ni][j]); kss += f * f; }
      kss += __shfl_xor(kss, 16, 64);
      kss += __shfl_xor(kss, 32, 64);
      knv[ni] = sqrtf(kss);
    }

    bf16x8 af = as_bf(au);
    f32x4 accS[4];
#pragma unroll
    for (int ni = 0; ni < 4; ni++) {
      f32x4 z = {0.f, 0.f, 0.f, 0.f};
      accS[ni] = __builtin_amdgcn_mfma_f32_16x16x32_bf16(af, as_bf(bu[ni]), z, 0, 0, 0);
    }

    for (int e = tid; e < 2048; e += 256) {
      int d = e & 31, q = e >> 5;
      VT[d * 72 + q] = Vs[q * 32 + d];
    }

    const float scale = fmaxf(tau[h] + 2.302585092994046f, 0.01f);
#pragma unroll
    for (int r = 0; r < 4; r++) {
      int p = wave * 16 + quad * 4 + r;
      float qnp = __shfl(qnv, quad * 4 + r, 64);
      int cp = scode[p];
      float sv[4];
#pragma unroll
      for (int ni = 0; ni < 4; ni++) {
        int q = ni * 16 + lm;
        float denom = fmaxf(qnp * knv[ni], 1e-6f);
        int dr = (p >> 3) - (q >> 3) + 7, dc = (p & 7) - (q & 7) + 7;
        float bv = tblh[cur][dr * 15 + dc];
        float mask = (cp == scode[q]) ? 0.f : -100.f;
        sv[ni] = accS[ni][r] * scale * __builtin_amdgcn_rcpf(denom) + bv + mask;
      }
      float m = fmaxf(fmaxf(sv[0], sv[1]), fmaxf(sv[2], sv[3]));
#pragma unroll
      for (int off = 1; off < 16; off <<= 1) m = fmaxf(m, __shfl_xor(m, off, 64));
      float s = 0.f;
#pragma unroll
      for (int ni = 0; ni < 4; ni++) { sv[ni] = __expf(sv[ni] - m); s += sv[ni]; }
#pragma unroll
      for (int off = 1; off < 16; off <<= 1) s += __shfl_xor(s, off, 64);
      float inv = __builtin_amdgcn_rcpf(s);
#pragma unroll
      for (int ni = 0; ni < 4; ni++)
        Pb[p * 72 + ni * 16 + lm] = f2bf(sv[ni] * inv);
    }

    __syncthreads();   // B: VT complete; all reads of Qs/Ks/Vs done

    if (hh < 7) {
      const size_t g = gs0 + (size_t)(h + 1) * 32;
      g2lds16(QKV + g, qdst);
      g2lds16(QKV + g + 512, kdst);
      g2lds16(QKV + g + 1024, vdst);
      for (int e = tid; e < 225; e += 256) tblh[cur ^ 1][e] = tblT[(h + 1) * 225 + e];
    }

    bf16x8 paf[2];
#pragma unroll
    for (int kc = 0; kc < 2; kc++)
      paf[kc] = *reinterpret_cast<const bf16x8*>(&Pb[(wave * 16 + lm) * 72 + kc * 32 + quad * 8]);
    f32x4 accO[2];
#pragma unroll
    for (int n2 = 0; n2 < 2; n2++) {
      f32x4 z = {0.f, 0.f, 0.f, 0.f};
#pragma unroll
      for (int kc = 0; kc < 2; kc++) {
        bf16x8 vb = *reinterpret_cast<const bf16x8*>(&VT[(n2 * 16 + lm) * 72 + kc * 32 + quad * 8]);
        z = __builtin_amdgcn_mfma_f32_16x16x32_bf16(paf[kc], vb, z, 0, 0, 0);
      }
      accO[n2] = z;
    }
#pragma unroll
    for (int n2 = 0; n2 < 2; n2++)
#pragma unroll
      for (int r = 0; r < 4; r++) {
        int p = wave * 16 + quad * 4 + r;
        Om[obase + (size_t)p * 512 + h * 32 + n2 * 16 + lm] = f2bf(accO[n2][r]);
      }
  }
}

// ---------- LN1: wave-per-token un-shift gather + layernorm + residual -> x1 bf16 ----------
__global__ __launch_bounds__(256) void ln1_kernel(
    const float* __restrict__ x, const unsigned short* __restrict__ proj,
    const float* __restrict__ g, const float* __restrict__ b,
    unsigned short* __restrict__ x1b)
{
  int tkn = blockIdx.x * 4 + (threadIdx.x >> 6);
  int lane = threadIdx.x & 63;
  int bb = tkn >> 12, s = tkn & 4095;
  int h_ = s >> 6, w_ = s & 63;
  int r = (h_ + 60) & 63, cc = (w_ + 60) & 63;
  int wi = (r >> 3) * 8 + (cc >> 3);
  int p = (r & 7) * 8 + (cc & 7);
  size_t src = ((size_t)bb * 4096 + wi * 64 + p) * 512 + lane * 8;
  u16x8 pv = *(const u16x8*)&proj[src];
  float v[8]; float ls = 0.f, lq = 0.f;
#pragma unroll
  for (int j = 0; j < 8; j++) { v[j] = bf2f(pv[j]); ls += v[j]; lq += v[j] * v[j]; }
#pragma unroll
  for (int off = 1; off < 64; off <<= 1) {
    ls += __shfl_xor(ls, off, 64);
    lq += __shfl_xor(lq, off, 64);
  }
  float mean = ls * (1.f / 512.f);
  float rstd = rsqrtf(lq * (1.f / 512.f) - mean * mean + 1e-6f);
  int c = lane * 8;
  size_t o = (size_t)tkn * 512 + c;
  float4 xa = *(const float4*)&x[o], xb = *(const float4*)&x[o + 4];
  float4 ga = *(const float4*)&g[c], gb = *(const float4*)&g[c + 4];
  float4 ba = *(const float4*)&b[c], bb4 = *(const float4*)&b[c + 4];
  u16x8 ov;
  ov[0] = f2bf((v[0] - mean) * rstd * ga.x + ba.x + xa.x);
  ov[1] = f2bf((v[1] - mean) * rstd * ga.y + ba.y + xa.y);
  ov[2] = f2bf((v[2] - mean) * rstd * ga.z + ba.z + xa.z);
  ov[3] = f2bf((v[3] - mean) * rstd * ga.w + ba.w + xa.w);
  ov[4] = f2bf((v[4] - mean) * rstd * gb.x + bb4.x + xb.x);
  ov[5] = f2bf((v[5] - mean) * rstd * gb.y + bb4.y + xb.y);
  ov[6] = f2bf((v[6] - mean) * rstd * gb.z + bb4.z + xb.z);
  ov[7] = f2bf((v[7] - mean) * rstd * gb.w + bb4.w + xb.w);
  *(u16x8*)&x1b[o] = ov;
}

// ---------- LN2 + residual -> out fp32 (wave-per-token) ----------
__global__ __launch_bounds__(256) void ln2_kernel(
    const unsigned short* __restrict__ x1b, const unsigned short* __restrict__ h2,
    const float* __restrict__ g, const float* __restrict__ b,
    float* __restrict__ out)
{
  int tkn = blockIdx.x * 4 + (threadIdx.x >> 6);
  int lane = threadIdx.x & 63;
  int c = lane * 8;
  size_t o = (size_t)tkn * 512 + c;
  u16x8 hv = *(const u16x8*)&h2[o];
  float v[8]; float ls = 0.f, lq = 0.f;
#pragma unroll
  for (int j = 0; j < 8; j++) { v[j] = bf2f(hv[j]); ls += v[j]; lq += v[j] * v[j]; }
#pragma unroll
  for (int off = 1; off < 64; off <<= 1) {
    ls += __shfl_xor(ls, off, 64);
    lq += __shfl_xor(lq, off, 64);
  }
  float mean = ls * (1.f / 512.f);
  float rstd = rsqrtf(lq * (1.f / 512.f) - mean * mean + 1e-6f);
  u16x8 xv = *(const u16x8*)&x1b[o];
  float4 ga = *(const float4*)&g[c], gb = *(const float4*)&g[c + 4];
  float4 ba = *(const float4*)&b[c], bb4 = *(const float4*)&b[c + 4];
  float4 oa, ob;
  oa.x = bf2f(xv[0]) + (v[0] - mean) * rstd * ga.x + ba.x;
  oa.y = bf2f(xv[1]) + (v[1] - mean) * rstd * ga.y + ba.y;
  oa.z = bf2f(xv[2]) + (v[2] - mean) * rstd * ga.z + ba.z;
  oa.w = bf2f(xv[3]) + (v[3] - mean) * rstd * ga.w + ba.w;
  ob.x = bf2f(xv[4]) + (v[4] - mean) * rstd * gb.x + bb4.x;
  ob.y = bf2f(xv[5]) + (v[5] - mean) * rstd * gb.y + bb4.y;
  ob.z = bf2f(xv[6]) + (v[6] - mean) * rstd * gb.z + bb4.z;
  ob.w = bf2f(xv[7]) + (v[7] - mean) * rstd * gb.w + bb4.w;
  *(float4*)&out[o] = oa;
  *(float4*)&out[o + 4] = ob;
}

// ---------- launcher ----------
extern "C" void kernel_launch(void* const* d_in, const int* in_sizes, int n_in,
                              void* d_out, int out_size, void* d_ws, size_t ws_size,
                              hipStream_t stream) {
  const float* x      = (const float*)d_in[0];
  const float* q_w    = (const float*)d_in[1];
  const float* q_b    = (const float*)d_in[2];
  const float* k_w    = (const float*)d_in[3];
  const float* v_w    = (const float*)d_in[4];
  const float* v_b    = (const float*)d_in[5];
  const float* proj_w = (const float*)d_in[6];
  const float* proj_b = (const float*)d_in[7];
  const float* tau    = (const float*)d_in[8];
  const float* cpb_w1 = (const float*)d_in[9];
  const float* cpb_b1 = (const float*)d_in[10];
  const float* cpb_w2 = (const float*)d_in[11];
  const float* cpb_b2 = (const float*)d_in[12];
  const float* n1g    = (const float*)d_in[13];
  const float* n1b    = (const float*)d_in[14];
  const float* n2g    = (const float*)d_in[15];
  const float* n2b    = (const float*)d_in[16];
  const float* mlp_w1 = (const float*)d_in[17];
  const float* mlp_b1 = (const float*)d_in[18];
  const float* mlp_w2 = (const float*)d_in[19];
  const float* mlp_b2 = (const float*)d_in[20];
  float* out = (float*)d_out;
  char* ws = (char*)d_ws;

  const size_t MB = 1048576;
  unsigned short* xw    = (unsigned short*)(ws + 0 * MB);
  unsigned short* Obuf  = (unsigned short*)(ws + 0 * MB);
  unsigned short* hbuf  = (unsigned short*)(ws + 0 * MB);
  unsigned short* qkv   = (unsigned short*)(ws + 64 * MB);
  unsigned short* projb = (unsigned short*)(ws + 64 * MB);
  unsigned short* x1b   = (unsigned short*)(ws + 128 * MB);
  unsigned short* h2b   = (unsigned short*)(ws + 192 * MB);
  unsigned short* qkvT = (unsigned short*)(ws + 320 * MB);
  unsigned short* pwT  = (unsigned short*)(ws + 320 * MB + 1572864);
  unsigned short* m1T  = (unsigned short*)(ws + 320 * MB + 2097152);
  unsigned short* m2T  = (unsigned short*)(ws + 320 * MB + 4194304);
  float* tbl           = (float*)         (ws + 320 * MB + 6291456);   // 16x225 f32
  float* qkv_b         = (float*)         (ws + 320 * MB + 6307840);

  transpose_cast<<<dim3(16, 16), 256, 0, stream>>>(q_w,    qkvT,          512, 512);
  transpose_cast<<<dim3(16, 16), 256, 0, stream>>>(k_w,    qkvT + 262144, 512, 512);
  transpose_cast<<<dim3(16, 16), 256, 0, stream>>>(v_w,    qkvT + 524288, 512, 512);
  transpose_cast<<<dim3(16, 16), 256, 0, stream>>>(proj_w, pwT, 512, 512);
  transpose_cast<<<dim3(64, 16), 256, 0, stream>>>(mlp_w1, m1T, 512, 2048);
  transpose_cast<<<dim3(16, 64), 256, 0, stream>>>(mlp_w2, m2T, 2048, 512);
  qkv_bias_kernel<<<6, 256, 0, stream>>>(q_b, v_b, qkv_b);
  cpb_kernel<<<225, 512, 0, stream>>>(cpb_w1, cpb_b1, cpb_w2, cpb_b2, tbl);
  shift_part<<<32768, 256, 0, stream>>>(x, xw);
  // fused QKV: [65536,512] x [512,1536]; T = 256*6 = 1536 tiles
  gemm256<0><<<256, 512, 0, stream>>>(xw, qkvT, qkv_b, qkv, 1536, 512, 6, 1536);
  attn_mfma<<<2048, 256, 0, stream>>>(qkv, tau, tbl, Obuf);
  gemm256<0><<<256, 512, 0, stream>>>(Obuf, pwT, proj_b, projb, 512, 512, 2, 512);
  ln1_kernel<<<16384, 256, 0, stream>>>(x, projb, n1g, n1b, x1b);
  for (int c2 = 0; c2 < 2; c2++) {
    const unsigned short* a = x1b + (size_t)c2 * 32768 * 512;
    unsigned short* h2p = h2b + (size_t)c2 * 32768 * 512;
    gemm256<1><<<256, 512, 0, stream>>>(a, m1T, mlp_b1, hbuf, 2048, 512, 8, 1024);
    gemm256<0><<<256, 512, 0, stream>>>(hbuf, m2T, mlp_b2, h2p, 512, 2048, 2, 256);
  }
  ln2_kernel<<<16384, 256, 0, stream>>>(x1b, h2b, n2g, n2b, out);
}